// Round 8
// baseline (578.000 us; speedup 1.0000x reference)
//
#include <hip/hip_runtime.h>

#define Gn 4
#define Nn 50000
#define En 800000
#define Bq 32
#define F_IN 64
#define Hn 128
#define NNODES 50000
#define NBK 196     // dest buckets per graph (dest >> 8), 256 nodes each
#define EB 98       // edge chunks per graph (8192 edges each)

using v8s = __attribute__((ext_vector_type(8))) short;
using v4f = __attribute__((ext_vector_type(4))) float;
using v2f = __attribute__((ext_vector_type(2))) float;

// ---- bf16 helpers (RNE) ----
__device__ __forceinline__ float bf2f(unsigned short u) {
    unsigned int x = ((unsigned int)u) << 16;
    float f; __builtin_memcpy(&f, &x, 4); return f;
}
__device__ __forceinline__ unsigned short f2bf(float f) {
    unsigned int x; __builtin_memcpy(&x, &f, 4);
    x = (x + 0x7fffu + ((x >> 16) & 1u)) >> 16;
    return (unsigned short)x;
}
// unpack u32 holding 2 bf16 -> float2 {even, odd}
__device__ __forceinline__ v2f up2(unsigned int w) {
    unsigned int lo = w << 16, hi = w & 0xffff0000u;
    float flo, fhi;
    __builtin_memcpy(&flo, &lo, 4);
    __builtin_memcpy(&fhi, &hi, 4);
    v2f v = {flo, fhi};
    return v;
}

// ---------------- phase 1: coarse bucket totals + per-chunk histograms ----------------
__global__ __launch_bounds__(256) void k_btot(const int* __restrict__ ei, int* __restrict__ btot,
                                              int* __restrict__ chist) {
    __shared__ int h[NBK];
    int g = blockIdx.y;
    const int* col = ei + (size_t)g * 2 * En + En;
    for (int i = threadIdx.x; i < NBK; i += 256) h[i] = 0;
    __syncthreads();
    int e0 = blockIdx.x * 8192, e1 = min(e0 + 8192, En);
    for (int i = e0 / 4 + threadIdx.x; i < e1 / 4; i += 256) {
        int4 c = ((const int4*)col)[i];
        atomicAdd(&h[c.x >> 8], 1);
        atomicAdd(&h[c.y >> 8], 1);
        atomicAdd(&h[c.z >> 8], 1);
        atomicAdd(&h[c.w >> 8], 1);
    }
    __syncthreads();
    int* ch = chist + ((size_t)g * EB + blockIdx.x) * NBK;
    for (int i = threadIdx.x; i < NBK; i += 256) {
        int v = h[i];
        ch[i] = v;
        if (v) atomicAdd(&btot[g * NBK + i], v);
    }
}

// ---------------- phase 2: scan bucket totals -> bases + global cursors ----------------
__global__ __launch_bounds__(256) void k_bbase(const int* __restrict__ btot, int* __restrict__ bbase,
                                               int* __restrict__ bcur) {
    __shared__ int s[256];
    int g = blockIdx.x, t = threadIdx.x;
    int v = (t < NBK) ? btot[g * NBK + t] : 0;
    s[t] = v;
    __syncthreads();
    for (int d = 1; d < 256; d <<= 1) {
        int u = (t >= d) ? s[t - d] : 0;
        __syncthreads();
        s[t] += u;
        __syncthreads();
    }
    if (t < NBK) { int b = s[t] - v; bbase[g * NBK + t] = b; bcur[g * NBK + t] = b; }
}

// ---------------- phase 3: bucketize (reuses per-chunk histograms; one edge scan) ----------------
__global__ __launch_bounds__(256) void k_bucket(const int* __restrict__ ei, int* __restrict__ bcur,
                                                unsigned int* __restrict__ pairs,
                                                const int* __restrict__ chist) {
    __shared__ int h[NBK];
    __shared__ int gbase[NBK];
    int g = blockIdx.y;
    const int* row = ei + (size_t)g * 2 * En;
    const int* col = row + En;
    unsigned int* pg = pairs + (size_t)g * En;
    const int* ch = chist + ((size_t)g * EB + blockIdx.x) * NBK;
    for (int i = threadIdx.x; i < NBK; i += 256) {
        int cnt = ch[i];
        gbase[i] = cnt ? atomicAdd(&bcur[g * NBK + i], cnt) : 0;
        h[i] = 0;  // local cursor
    }
    __syncthreads();
    int e0 = blockIdx.x * 8192, e1 = min(e0 + 8192, En);
    for (int i = e0 / 4 + threadIdx.x; i < e1 / 4; i += 256) {
        int4 c = ((const int4*)col)[i];
        int4 r = ((const int4*)row)[i];
        int p;
        p = gbase[c.x >> 8] + atomicAdd(&h[c.x >> 8], 1); pg[p] = ((unsigned)r.x << 16) | (unsigned)c.x;
        p = gbase[c.y >> 8] + atomicAdd(&h[c.y >> 8], 1); pg[p] = ((unsigned)r.y << 16) | (unsigned)c.y;
        p = gbase[c.z >> 8] + atomicAdd(&h[c.z >> 8], 1); pg[p] = ((unsigned)r.z << 16) | (unsigned)c.z;
        p = gbase[c.w >> 8] + atomicAdd(&h[c.w >> 8], 1); pg[p] = ((unsigned)r.w << 16) | (unsigned)c.w;
    }
}

// ---------------- phase 4 (fused): per-bucket count + scan -> off/dinv, then LDS-cursor fill ----------------
__global__ __launch_bounds__(256) void k_fillb2(const unsigned int* __restrict__ pairs,
                                                const int* __restrict__ bbase, const int* __restrict__ btot,
                                                int* __restrict__ off, float* __restrict__ dinv,
                                                unsigned short* __restrict__ srcs) {
    __shared__ int h[256], sc[256], curL[256];
    int g = blockIdx.y, b = blockIdx.x, t = threadIdx.x;
    int beg = bbase[g * NBK + b], cnt = btot[g * NBK + b];
    const unsigned int* pg = pairs + (size_t)g * En + beg;
    unsigned short* sg = srcs + (size_t)g * En;
    h[t] = 0;
    __syncthreads();
    for (int i = t; i < cnt; i += 256) atomicAdd(&h[pg[i] & 255], 1);
    __syncthreads();
    int d = h[t];
    sc[t] = d;
    __syncthreads();
    for (int dd = 1; dd < 256; dd <<= 1) {
        int u = (t >= dd) ? sc[t - dd] : 0;
        __syncthreads();
        sc[t] += u;
        __syncthreads();
    }
    int myoff = beg + sc[t] - d;  // exclusive
    int node = b * 256 + t;
    if (node < Nn) {
        off[g * (Nn + 1) + node] = myoff;
        dinv[g * Nn + node] = rsqrtf((float)d + 1.0f);
    }
    if (b == NBK - 1 && t == 255) off[g * (Nn + 1) + Nn] = beg + sc[255];
    curL[t] = myoff;
    __syncthreads();
    for (int i = t; i < cnt; i += 256) {
        unsigned int pr = pg[i];
        int pos = atomicAdd(&curL[pr & 255], 1);
        sg[pos] = (unsigned short)(pr >> 16);
    }
}

// ---------------- cast + pre-scale: xbs = bf16(x * dinv), all graphs ----------------
__global__ __launch_bounds__(256) void k_cast(const float* __restrict__ x, const float* __restrict__ dinv,
                                              unsigned short* __restrict__ xbs) {
    int g = blockIdx.y;
    int i = blockIdx.x * 256 + threadIdx.x;  // float4 index within graph
    if (i >= Nn * 16) return;
    float dc = dinv[g * Nn + (i >> 4)];
    float4 v = *(const float4*)&x[(size_t)g * Nn * 64 + i * 4];
    ushort4 u = make_ushort4(f2bf(v.x * dc), f2bf(v.y * dc), f2bf(v.z * dc), f2bf(v.w * dc));
    *(ushort4*)&xbs[(size_t)g * Nn * 64 + i * 4] = u;
}

// ---------------- agg 64-feat: full wave per node, 8 edge slots, packed-f32 accumulate ----------------
__global__ __launch_bounds__(256) void k_agg1(const unsigned short* __restrict__ xs_, const int* __restrict__ off_,
                                              const unsigned short* __restrict__ srcs_,
                                              const float* __restrict__ dinv_, unsigned short* __restrict__ z1_) {
    int g = blockIdx.y;
    const unsigned short* xs = xs_ + (size_t)g * Nn * 64;
    const int* off = off_ + g * (Nn + 1);
    const unsigned short* srcs = srcs_ + (size_t)g * En;
    unsigned short* z1 = z1_ + (size_t)g * Nn * 64;
    int node = blockIdx.x * 4 + (threadIdx.x >> 6);
    int lane = threadIdx.x & 63;
    int sub = lane >> 3;   // edge slot 0..7
    int fo = lane & 7;     // feature octile: feats [fo*8, fo*8+8)
    int beg = off[node], end = off[node + 1];
    int d = end - beg;
    int dm1 = max(d - 1, 0);
    int nst = (d + 7) >> 3;            // steps of 8 edges (one node per wave)
    v2f acc[4] = {};
    // rolling pipeline: clamped sids (always-valid loads), step st+1 gather
    // issues before consuming step st; mask-fma zeroes straggler slots.
    int sb = srcs[beg + min(sub, dm1)];
    uint4 c = *(const uint4*)&xs[(unsigned)sb * 64 + fo * 8];
    sb = srcs[beg + min(8 + sub, dm1)];
    for (int st = 0; st < nst; ++st) {
        uint4 n = *(const uint4*)&xs[(unsigned)sb * 64 + fo * 8];
        sb = srcs[beg + min((st + 2) * 8 + sub, dm1)];
        float m = (st * 8 + sub < d) ? 1.f : 0.f;
        v2f m2 = {m, m};
        acc[0] += m2 * up2(c.x);
        acc[1] += m2 * up2(c.y);
        acc[2] += m2 * up2(c.z);
        acc[3] += m2 * up2(c.w);
        c = n;
    }
#pragma unroll
    for (int p = 0; p < 4; ++p) {
        float ax = acc[p].x, ay = acc[p].y;
        ax += __shfl_xor(ax, 8, 64);  ay += __shfl_xor(ay, 8, 64);
        ax += __shfl_xor(ax, 16, 64); ay += __shfl_xor(ay, 16, 64);
        ax += __shfl_xor(ax, 32, 64); ay += __shfl_xor(ay, 32, 64);
        acc[p].x = ax; acc[p].y = ay;
    }
    if (sub == 0) {
        float dc = dinv_[g * Nn + node];
        uint4 ow = *(const uint4*)&xs[(unsigned)node * 64 + fo * 8];
        v2f s0 = up2(ow.x), s1 = up2(ow.y), s2 = up2(ow.z), s3 = up2(ow.w);
        ushort4 o0, o1;
        o0.x = f2bf((acc[0].x + s0.x) * dc);
        o0.y = f2bf((acc[0].y + s0.y) * dc);
        o0.z = f2bf((acc[1].x + s1.x) * dc);
        o0.w = f2bf((acc[1].y + s1.y) * dc);
        o1.x = f2bf((acc[2].x + s2.x) * dc);
        o1.y = f2bf((acc[2].y + s2.y) * dc);
        o1.z = f2bf((acc[3].x + s3.x) * dc);
        o1.w = f2bf((acc[3].y + s3.y) * dc);
        *(ushort4*)&z1[(unsigned)node * 64 + fo * 8] = o0;
        *(ushort4*)&z1[(unsigned)node * 64 + fo * 8 + 4] = o1;
    }
}

// ---------------- agg 128-feat: full wave per node, 8 edge slots, packed-f32 accumulate ----------------
__global__ __launch_bounds__(256) void k_agg2(const unsigned short* __restrict__ h_, const int* __restrict__ off_,
                                              const unsigned short* __restrict__ srcs_,
                                              const float* __restrict__ dinv_, unsigned short* __restrict__ z2_) {
    int g = blockIdx.y;
    const unsigned short* h = h_ + (size_t)g * Nn * 128;
    const int* off = off_ + g * (Nn + 1);
    const unsigned short* srcs = srcs_ + (size_t)g * En;
    unsigned short* z2 = z2_ + (size_t)g * Nn * 128;
    int node = blockIdx.x * 4 + (threadIdx.x >> 6);
    int lane = threadIdx.x & 63;
    int sub = lane >> 3;   // edge slot 0..7
    int fo = lane & 7;     // feature 16-tile: feats [fo*16, fo*16+16)
    int beg = off[node], end = off[node + 1];
    int d = end - beg;
    int dm1 = max(d - 1, 0);
    int nst = (d + 7) >> 3;
    v2f acc[8] = {};
    int sb = srcs[beg + min(sub, dm1)];
    const uint4* rp = (const uint4*)&h[(unsigned)sb * 128 + fo * 16];
    uint4 c0 = rp[0], c1 = rp[1];
    sb = srcs[beg + min(8 + sub, dm1)];
    for (int st = 0; st < nst; ++st) {
        const uint4* rpn = (const uint4*)&h[(unsigned)sb * 128 + fo * 16];
        uint4 n0 = rpn[0], n1 = rpn[1];
        sb = srcs[beg + min((st + 2) * 8 + sub, dm1)];
        float m = (st * 8 + sub < d) ? 1.f : 0.f;
        v2f m2 = {m, m};
        acc[0] += m2 * up2(c0.x);
        acc[1] += m2 * up2(c0.y);
        acc[2] += m2 * up2(c0.z);
        acc[3] += m2 * up2(c0.w);
        acc[4] += m2 * up2(c1.x);
        acc[5] += m2 * up2(c1.y);
        acc[6] += m2 * up2(c1.z);
        acc[7] += m2 * up2(c1.w);
        c0 = n0; c1 = n1;
    }
#pragma unroll
    for (int p = 0; p < 8; ++p) {
        float ax = acc[p].x, ay = acc[p].y;
        ax += __shfl_xor(ax, 8, 64);  ay += __shfl_xor(ay, 8, 64);
        ax += __shfl_xor(ax, 16, 64); ay += __shfl_xor(ay, 16, 64);
        ax += __shfl_xor(ax, 32, 64); ay += __shfl_xor(ay, 32, 64);
        acc[p].x = ax; acc[p].y = ay;
    }
    if (sub == 0) {
        float dc = dinv_[g * Nn + node];
        const unsigned short* op = &h[(unsigned)node * 128 + fo * 16];
        unsigned short* zp = &z2[(unsigned)node * 128 + fo * 16];
#pragma unroll
        for (int p4 = 0; p4 < 2; ++p4) {
            uint4 ow = *(const uint4*)(op + p4 * 8);
            v2f s0 = up2(ow.x), s1 = up2(ow.y), s2 = up2(ow.z), s3 = up2(ow.w);
            ushort4 oa, ob;
            oa.x = f2bf((acc[p4 * 4 + 0].x + s0.x) * dc);
            oa.y = f2bf((acc[p4 * 4 + 0].y + s0.y) * dc);
            oa.z = f2bf((acc[p4 * 4 + 1].x + s1.x) * dc);
            oa.w = f2bf((acc[p4 * 4 + 1].y + s1.y) * dc);
            ob.x = f2bf((acc[p4 * 4 + 2].x + s2.x) * dc);
            ob.y = f2bf((acc[p4 * 4 + 2].y + s2.y) * dc);
            ob.z = f2bf((acc[p4 * 4 + 3].x + s3.x) * dc);
            ob.w = f2bf((acc[p4 * 4 + 3].y + s3.y) * dc);
            *(ushort4*)(zp + p4 * 8) = oa;
            *(ushort4*)(zp + p4 * 8 + 4) = ob;
        }
    }
}

// ---------------- MFMA mm, all graphs: out = relu(zin@W + b) [* dinv if SCALE] ----------------
template <int K, bool SCALE>
__global__ __launch_bounds__(256) void k_mmfma(const unsigned short* __restrict__ zin_,
                                               const float* __restrict__ W, const float* __restrict__ bias,
                                               const float* __restrict__ dinv_,
                                               unsigned short* __restrict__ outp_) {
    __shared__ __align__(16) unsigned short Wt[128 * (K + 8)];
    __shared__ __align__(16) unsigned short At[32 * (K + 8)];
    int g = blockIdx.y;
    const unsigned short* zin = zin_ + (size_t)g * Nn * K;
    const float* dinv = dinv_ + g * Nn;
    unsigned short* outp = outp_ + (size_t)g * Nn * 128;
    int t = threadIdx.x;
    int base = blockIdx.x * 32;

#pragma unroll
    for (int i = 0; i < K * 128 / 256; ++i) {
        int idx = i * 256 + t;
        int k = idx >> 7, n = idx & 127;
        Wt[n * (K + 8) + k] = f2bf(W[idx]);
    }
    {
        int r = t >> 3, cb = (t & 7) * (K / 8);
        long grow = base + r;
#pragma unroll
        for (int j = 0; j < K / 32; ++j) {
            ushort4 u = make_ushort4(0, 0, 0, 0);
            if (grow < Nn) u = *(const ushort4*)&zin[grow * K + cb + j * 4];
            *(ushort4*)&At[r * (K + 8) + cb + j * 4] = u;
        }
    }
    __syncthreads();

    int w = t >> 6, lane = t & 63;
    int wm = w & 1, wn = w >> 1;
    int m = lane & 15, q = lane >> 4;
    v4f acc[4] = {};
    const unsigned short* Ap = &At[(wm * 16 + m) * (K + 8) + q * 8];
    const unsigned short* Bp = &Wt[(wn * 64 + m) * (K + 8) + q * 8];
    const int rstep = 16 * (K + 8);
#pragma unroll
    for (int ks = 0; ks < K / 32; ++ks) {
        v8s a = *(const v8s*)(Ap + ks * 32);
        v8s b0 = *(const v8s*)(Bp + 0 * rstep + ks * 32);
        v8s b1 = *(const v8s*)(Bp + 1 * rstep + ks * 32);
        v8s b2 = *(const v8s*)(Bp + 2 * rstep + ks * 32);
        v8s b3 = *(const v8s*)(Bp + 3 * rstep + ks * 32);
        acc[0] = __builtin_amdgcn_mfma_f32_16x16x32_bf16(a, b0, acc[0], 0, 0, 0);
        acc[1] = __builtin_amdgcn_mfma_f32_16x16x32_bf16(a, b1, acc[1], 0, 0, 0);
        acc[2] = __builtin_amdgcn_mfma_f32_16x16x32_bf16(a, b2, acc[2], 0, 0, 0);
        acc[3] = __builtin_amdgcn_mfma_f32_16x16x32_bf16(a, b3, acc[3], 0, 0, 0);
    }

    int col0 = wn * 64 + m;
    int rbase = base + wm * 16 + q * 4;
    float dv[4];
#pragma unroll
    for (int rg = 0; rg < 4; ++rg)
        dv[rg] = SCALE ? ((rbase + rg < Nn) ? dinv[rbase + rg] : 1.f) : 1.f;
#pragma unroll
    for (int nt = 0; nt < 4; ++nt) {
        float bc = bias[col0 + nt * 16];
#pragma unroll
        for (int rg = 0; rg < 4; ++rg) {
            int row = rbase + rg;
            if (row < Nn) {
                float o = fmaxf(acc[nt][rg] + bc, 0.f);
                outp[(long)row * 128 + col0 + nt * 16] = f2bf(o * dv[rg]);
            }
        }
    }
}

// ---------------- segment mean pool (batch sorted), all graphs ----------------
__global__ __launch_bounds__(128) void k_pool(const unsigned short* __restrict__ y_, const int* __restrict__ bat,
                                              float* __restrict__ emb_sum, float* __restrict__ cnt) {
    int g = blockIdx.y;
    const unsigned short* y = y_ + (size_t)g * Nn * 128;
    const int* batch = bat + (size_t)g * Nn;
    int f = threadIdx.x;
    int start = blockIdx.x * 64;
    int end = min(start + 64, Nn);
    if (start >= Nn) return;
    float acc = 0.f;
    int cacc = 0;
    int cur = batch[start];
    for (int i = start; i < end; ++i) {
        int b = batch[i];
        if (b != cur) {
            atomicAdd(&emb_sum[(g * Bq + cur) * Hn + f], acc);
            if (f == 0) atomicAdd(&cnt[g * Bq + cur], (float)cacc);
            acc = 0.f; cacc = 0; cur = b;
        }
        acc += bf2f(y[(long)i * Hn + f]);
        cacc++;
    }
    atomicAdd(&emb_sum[(g * Bq + cur) * Hn + f], acc);
    if (f == 0) atomicAdd(&cnt[g * Bq + cur], (float)cacc);
}

// ---------------- whole MHA: one block per batch element b ----------------
__global__ __launch_bounds__(128) void k_attn(const float* __restrict__ emb_sum, const float* __restrict__ cnt,
                                              const float* __restrict__ ipw, const float* __restrict__ ipb,
                                              const float* __restrict__ opw, const float* __restrict__ opb,
                                              float* __restrict__ pooled) {
    int b = blockIdx.x;
    int f = threadIdx.x;
    __shared__ float es[4][128], qs[4][128], ks[4][128], vs[4][128], sc[128], cx[4][128];
#pragma unroll
    for (int g = 0; g < 4; ++g) {
        float c = cnt[g * Bq + b];
        es[g][f] = (c > 0.f) ? emb_sum[(g * Bq + b) * Hn + f] / c : 0.f;
    }
    __syncthreads();
#pragma unroll
    for (int g = 0; g < 4; ++g) {
        float q = ipb[f], k = ipb[Hn + f], v = ipb[2 * Hn + f];
        for (int j = 0; j < Hn; ++j) {
            float e = es[g][j];
            q += e * ipw[f * Hn + j];
            k += e * ipw[(Hn + f) * Hn + j];
            v += e * ipw[(2 * Hn + f) * Hn + j];
        }
        qs[g][f] = q; ks[g][f] = k; vs[g][f] = v;
    }
    __syncthreads();
    {
        int h = f >> 4, g = (f >> 2) & 3, kk = f & 3;
        float s = 0.f;
        for (int d = 0; d < 16; ++d) s += qs[g][h * 16 + d] * ks[kk][h * 16 + d];
        sc[f] = s * 0.25f;
    }
    __syncthreads();
    {
        int h = f >> 4;
#pragma unroll
        for (int g = 0; g < 4; ++g) {
            int bi = h * 16 + g * 4;
            float s0 = sc[bi], s1 = sc[bi + 1], s2 = sc[bi + 2], s3 = sc[bi + 3];
            float m = fmaxf(fmaxf(s0, s1), fmaxf(s2, s3));
            float e0 = __expf(s0 - m), e1 = __expf(s1 - m), e2 = __expf(s2 - m), e3 = __expf(s3 - m);
            float rinv = 1.f / (e0 + e1 + e2 + e3);
            cx[g][f] = (e0 * vs[0][f] + e1 * vs[1][f] + e2 * vs[2][f] + e3 * vs[3][f]) * rinv;
        }
    }
    __syncthreads();
#pragma unroll
    for (int g = 0; g < 4; ++g) {
        float a = opb[f];
        for (int j = 0; j < Hn; ++j) a += cx[g][j] * opw[f * Hn + j];
        atomicAdd(&pooled[g * Hn + f], a * (1.0f / Bq));
    }
}

// ---------------- final: out[g,n] = (pooled[g] . lin_w[n] + lin_b[n]) * 60 + 50 ----------------
__global__ __launch_bounds__(256) void k_final(const float* __restrict__ pooled, const float* __restrict__ lw,
                                               const float* __restrict__ lb, float* __restrict__ out) {
    __shared__ float ps[512];
    int t = threadIdx.x;
    ps[t] = pooled[t];
    ps[t + 256] = pooled[t + 256];
    __syncthreads();
    int wave = t >> 6, lane = t & 63;
    int n = blockIdx.x * 4 + wave;
    if (n >= NNODES) return;
    float2 w = *(const float2*)&lw[(long)n * 128 + lane * 2];
    float a0 = w.x * ps[0 * 128 + lane * 2] + w.y * ps[0 * 128 + lane * 2 + 1];
    float a1 = w.x * ps[1 * 128 + lane * 2] + w.y * ps[1 * 128 + lane * 2 + 1];
    float a2 = w.x * ps[2 * 128 + lane * 2] + w.y * ps[2 * 128 + lane * 2 + 1];
    float a3 = w.x * ps[3 * 128 + lane * 2] + w.y * ps[3 * 128 + lane * 2 + 1];
#pragma unroll
    for (int off = 32; off > 0; off >>= 1) {
        a0 += __shfl_down(a0, off);
        a1 += __shfl_down(a1, off);
        a2 += __shfl_down(a2, off);
        a3 += __shfl_down(a3, off);
    }
    if (lane == 0) {
        float bn = lb[n];
        out[0 * NNODES + n] = (a0 + bn) * 60.f + 50.f;
        out[1 * NNODES + n] = (a1 + bn) * 60.f + 50.f;
        out[2 * NNODES + n] = (a2 + bn) * 60.f + 50.f;
        out[3 * NNODES + n] = (a3 + bn) * 60.f + 50.f;
    }
}

extern "C" void kernel_launch(void* const* d_in, const int* in_sizes, int n_in,
                              void* d_out, int out_size, void* d_ws, size_t ws_size,
                              hipStream_t stream) {
    const float* x   = (const float*)d_in[0];
    const int*   ei  = (const int*)d_in[1];
    const int*   bat = (const int*)d_in[2];
    const float* W1  = (const float*)d_in[3];
    const float* b1  = (const float*)d_in[4];
    const float* W2  = (const float*)d_in[5];
    const float* b2  = (const float*)d_in[6];
    const float* ipw = (const float*)d_in[7];
    const float* ipb = (const float*)d_in[8];
    const float* opw = (const float*)d_in[9];
    const float* opb = (const float*)d_in[10];
    const float* lw  = (const float*)d_in[11];
    const float* lb  = (const float*)d_in[12];
    float* out = (float*)d_out;

    // workspace carve-up (~214 MB)
    char* p = (char*)d_ws;
    unsigned short* xbs = (unsigned short*)p;                 // [4][N,64]  bf16  25.6 MB
    unsigned short* z1  = (unsigned short*)(p + 25600000);    // [4][N,64]  bf16  25.6 MB
    unsigned short* y1b = (unsigned short*)(p + 51200000);    // [4][N,128] bf16  51.2 MB
    unsigned short* z2  = (unsigned short*)(p + 102400000);   // [4][N,128] bf16  51.2 MB
    unsigned int*   pairs = (unsigned int*)(p + 102400000);   // [4][E] uint 12.8 MB (alias z2; dead before agg2)
    int* chist = (int*)(p + 102400000 + (size_t)4 * En * 4);  // [4][EB][NBK] int 307 KB (alias z2 tail; dead before agg2)
    unsigned short* y2b = (unsigned short*)(p + 153600000);   // [4][N,128] bf16  51.2 MB
    char* meta = p + 204800000;
    int*   off  = (int*)meta;                                 // [4][N+1]
    float* dinv = (float*)(off + 4 * (Nn + 1));               // [4][N]
    int*   btot  = (int*)(dinv + 4 * Nn);                     // [4][NBK]
    int*   bbase = btot + 4 * NBK;                            // [4][NBK]
    int*   bcur  = bbase + 4 * NBK;                           // [4][NBK]
    unsigned short* srcs = (unsigned short*)(bcur + 4 * NBK); // [4][E] ushort 6.4 MB
    float* emb    = (float*)(srcs + (size_t)4 * En);          // [G,B,H]
    float* cnt    = emb + Gn * Bq * Hn;                       // [G,B]
    float* pooled = cnt + Gn * Bq;                            // [G,H]

    hipMemsetAsync(btot, 0, 4 * NBK * sizeof(int), stream);
    hipMemsetAsync(emb, 0, Gn * Bq * Hn * sizeof(float), stream);
    hipMemsetAsync(cnt, 0, Gn * Bq * sizeof(float), stream);
    hipMemsetAsync(pooled, 0, Gn * Hn * sizeof(float), stream);

    const int agGrid = (Nn + 3) / 4;                 // 12500 (4 nodes/block, 1 wave/node)
    const int mmGrid = (Nn + 31) / 32;               // 1563
    const int plGrid = (Nn + 63) / 64;               // 782
    const int ctGrid = (Nn * 16 + 255) / 256;        // 3125

    // CSR build: totals+chunk hists -> bases -> bucketize (hist reuse) -> fused fill
    k_btot<<<dim3(EB, Gn), 256, 0, stream>>>(ei, btot, chist);
    k_bbase<<<Gn, 256, 0, stream>>>(btot, bbase, bcur);
    k_bucket<<<dim3(EB, Gn), 256, 0, stream>>>(ei, bcur, pairs, chist);
    k_fillb2<<<dim3(NBK, Gn), 256, 0, stream>>>(pairs, bbase, btot, off, dinv, srcs);

    // GCN layers, all graphs per launch
    k_cast<<<dim3(ctGrid, Gn), 256, 0, stream>>>(x, dinv, xbs);
    k_agg1<<<dim3(agGrid, Gn), 256, 0, stream>>>(xbs, off, srcs, dinv, z1);
    k_mmfma<64, true><<<dim3(mmGrid, Gn), 256, 0, stream>>>(z1, W1, b1, dinv, y1b);
    k_agg2<<<dim3(agGrid, Gn), 256, 0, stream>>>(y1b, off, srcs, dinv, z2);
    k_mmfma<128, false><<<dim3(mmGrid, Gn), 256, 0, stream>>>(z2, W2, b2, dinv, y2b);
    k_pool<<<dim3(plGrid, Gn), 128, 0, stream>>>(y2b, bat, emb, cnt);

    k_attn<<<Bq, 128, 0, stream>>>(emb, cnt, ipw, ipb, opw, opb, pooled);
    k_final<<<(NNODES + 3) / 4, 256, 0, stream>>>(pooled, lw, lb, out);
}

// Round 10
// 506.108 us; speedup vs baseline: 1.1420x; 1.1420x over previous
//
#include <hip/hip_runtime.h>

#define Gn 4
#define Nn 50000
#define En 800000
#define Bq 32
#define F_IN 64
#define Hn 128
#define NNODES 50000
#define NBK 196     // dest buckets per graph (dest >> 8), 256 nodes each
#define EB 98       // edge chunks per graph (8192 edges each)

using v8s = __attribute__((ext_vector_type(8))) short;
using v4f = __attribute__((ext_vector_type(4))) float;
using v2f = __attribute__((ext_vector_type(2))) float;

// ---- bf16 helpers (RNE) ----
__device__ __forceinline__ float bf2f(unsigned short u) {
    unsigned int x = ((unsigned int)u) << 16;
    float f; __builtin_memcpy(&f, &x, 4); return f;
}
__device__ __forceinline__ unsigned short f2bf(float f) {
    unsigned int x; __builtin_memcpy(&x, &f, 4);
    x = (x + 0x7fffu + ((x >> 16) & 1u)) >> 16;
    return (unsigned short)x;
}

// ---- fp8 e4m3 helpers (OCP e4m3fn; HW cvt when available) ----
__device__ __forceinline__ float fp8_1(unsigned int b) {
    // software decode (fallback only)
    unsigned int s = (b & 0x80u) << 24;
    unsigned int em = b & 0x7fu;
    float f;
    if (em >= 8u) {
        unsigned int bits = s | (((em >> 3) + 120u) << 23) | ((em & 7u) << 20);
        __builtin_memcpy(&f, &bits, 4);
    } else {
        f = (float)em * 0.001953125f;  // 2^-9
        if (s) f = -f;
    }
    return f;
}
template <bool HI>
__device__ __forceinline__ v2f fp8pk(unsigned int w) {
#if __has_builtin(__builtin_amdgcn_cvt_pk_f32_fp8)
    auto r = __builtin_amdgcn_cvt_pk_f32_fp8(w, HI);
    v2f o = {r[0], r[1]};
    return o;
#else
    unsigned int b0 = HI ? ((w >> 16) & 0xffu) : (w & 0xffu);
    unsigned int b1 = HI ? ((w >> 24) & 0xffu) : ((w >> 8) & 0xffu);
    v2f o = {fp8_1(b0), fp8_1(b1)};
    return o;
#endif
}
__device__ __forceinline__ unsigned char f2fp8_sw(float f) {
    unsigned int b; __builtin_memcpy(&b, &f, 4);
    unsigned int s = (b >> 24) & 0x80u;
    unsigned int ae = b & 0x7fffffffu;
    float a; __builtin_memcpy(&a, &ae, 4);
    if (a >= 448.f) return (unsigned char)(s | 0x7eu);
    if (a < 0.0009765625f) return (unsigned char)s;
    unsigned int mr = ae + 0x0007ffffu + ((ae >> 20) & 1u);
    int e = (int)(mr >> 23) - 127;
    if (e >= -6) {
        unsigned int m3 = (mr >> 20) & 7u;
        return (unsigned char)(s | ((unsigned)(e + 7) << 3) | m3);
    }
    int mi = (int)(a * 512.f + 0.5f);
    if (mi > 7) mi = 7;
    return (unsigned char)(s | (unsigned)mi);
}
__device__ __forceinline__ unsigned char f2fp8(float f) {
#if __has_builtin(__builtin_amdgcn_cvt_pk_fp8_f32)
    unsigned int r = __builtin_amdgcn_cvt_pk_fp8_f32(f, f, 0u, false);
    return (unsigned char)(r & 0xffu);
#else
    return f2fp8_sw(f);
#endif
}

// ---------------- phase 1: coarse bucket totals + per-chunk histograms ----------------
__global__ __launch_bounds__(256) void k_btot(const int* __restrict__ ei, int* __restrict__ btot,
                                              int* __restrict__ chist) {
    __shared__ int h[NBK];
    int g = blockIdx.y;
    const int* col = ei + (size_t)g * 2 * En + En;
    for (int i = threadIdx.x; i < NBK; i += 256) h[i] = 0;
    __syncthreads();
    int e0 = blockIdx.x * 8192, e1 = min(e0 + 8192, En);
    for (int i = e0 / 4 + threadIdx.x; i < e1 / 4; i += 256) {
        int4 c = ((const int4*)col)[i];
        atomicAdd(&h[c.x >> 8], 1);
        atomicAdd(&h[c.y >> 8], 1);
        atomicAdd(&h[c.z >> 8], 1);
        atomicAdd(&h[c.w >> 8], 1);
    }
    __syncthreads();
    int* ch = chist + ((size_t)g * EB + blockIdx.x) * NBK;
    for (int i = threadIdx.x; i < NBK; i += 256) {
        int v = h[i];
        ch[i] = v;
        if (v) atomicAdd(&btot[g * NBK + i], v);
    }
}

// ---------------- phase 2: scan bucket totals -> bases + global cursors ----------------
__global__ __launch_bounds__(256) void k_bbase(const int* __restrict__ btot, int* __restrict__ bbase,
                                               int* __restrict__ bcur) {
    __shared__ int s[256];
    int g = blockIdx.x, t = threadIdx.x;
    int v = (t < NBK) ? btot[g * NBK + t] : 0;
    s[t] = v;
    __syncthreads();
    for (int d = 1; d < 256; d <<= 1) {
        int u = (t >= d) ? s[t - d] : 0;
        __syncthreads();
        s[t] += u;
        __syncthreads();
    }
    if (t < NBK) { int b = s[t] - v; bbase[g * NBK + t] = b; bcur[g * NBK + t] = b; }
}

// ---------------- phase 3: bucketize (reuses per-chunk histograms; one edge scan) ----------------
__global__ __launch_bounds__(256) void k_bucket(const int* __restrict__ ei, int* __restrict__ bcur,
                                                unsigned int* __restrict__ pairs,
                                                const int* __restrict__ chist) {
    __shared__ int h[NBK];
    __shared__ int gbase[NBK];
    int g = blockIdx.y;
    const int* row = ei + (size_t)g * 2 * En;
    const int* col = row + En;
    unsigned int* pg = pairs + (size_t)g * En;
    const int* ch = chist + ((size_t)g * EB + blockIdx.x) * NBK;
    for (int i = threadIdx.x; i < NBK; i += 256) {
        int cnt = ch[i];
        gbase[i] = cnt ? atomicAdd(&bcur[g * NBK + i], cnt) : 0;
        h[i] = 0;  // local cursor
    }
    __syncthreads();
    int e0 = blockIdx.x * 8192, e1 = min(e0 + 8192, En);
    for (int i = e0 / 4 + threadIdx.x; i < e1 / 4; i += 256) {
        int4 c = ((const int4*)col)[i];
        int4 r = ((const int4*)row)[i];
        int p;
        p = gbase[c.x >> 8] + atomicAdd(&h[c.x >> 8], 1); pg[p] = ((unsigned)r.x << 16) | (unsigned)c.x;
        p = gbase[c.y >> 8] + atomicAdd(&h[c.y >> 8], 1); pg[p] = ((unsigned)r.y << 16) | (unsigned)c.y;
        p = gbase[c.z >> 8] + atomicAdd(&h[c.z >> 8], 1); pg[p] = ((unsigned)r.z << 16) | (unsigned)c.z;
        p = gbase[c.w >> 8] + atomicAdd(&h[c.w >> 8], 1); pg[p] = ((unsigned)r.w << 16) | (unsigned)c.w;
    }
}

// ---------------- phase 4 (fused): per-bucket count + scan -> off/dinv, then LDS-cursor fill ----------------
__global__ __launch_bounds__(256) void k_fillb2(const unsigned int* __restrict__ pairs,
                                                const int* __restrict__ bbase, const int* __restrict__ btot,
                                                int* __restrict__ off, float* __restrict__ dinv,
                                                unsigned short* __restrict__ srcs) {
    __shared__ int h[256], sc[256], curL[256];
    int g = blockIdx.y, b = blockIdx.x, t = threadIdx.x;
    int beg = bbase[g * NBK + b], cnt = btot[g * NBK + b];
    const unsigned int* pg = pairs + (size_t)g * En + beg;
    unsigned short* sg = srcs + (size_t)g * En;
    h[t] = 0;
    __syncthreads();
    for (int i = t; i < cnt; i += 256) atomicAdd(&h[pg[i] & 255], 1);
    __syncthreads();
    int d = h[t];
    sc[t] = d;
    __syncthreads();
    for (int dd = 1; dd < 256; dd <<= 1) {
        int u = (t >= dd) ? sc[t - dd] : 0;
        __syncthreads();
        sc[t] += u;
        __syncthreads();
    }
    int myoff = beg + sc[t] - d;  // exclusive
    int node = b * 256 + t;
    if (node < Nn) {
        off[g * (Nn + 1) + node] = myoff;
        dinv[g * Nn + node] = rsqrtf((float)d + 1.0f);
    }
    if (b == NBK - 1 && t == 255) off[g * (Nn + 1) + Nn] = beg + sc[255];
    curL[t] = myoff;
    __syncthreads();
    for (int i = t; i < cnt; i += 256) {
        unsigned int pr = pg[i];
        int pos = atomicAdd(&curL[pr & 255], 1);
        sg[pos] = (unsigned short)(pr >> 16);
    }
}

// ---------------- cast + pre-scale: xbs = bf16(x * dinv), all graphs ----------------
__global__ __launch_bounds__(256) void k_cast(const float* __restrict__ x, const float* __restrict__ dinv,
                                              unsigned short* __restrict__ xbs) {
    int g = blockIdx.y;
    int i = blockIdx.x * 256 + threadIdx.x;  // float4 index within graph
    if (i >= Nn * 16) return;
    float dc = dinv[g * Nn + (i >> 4)];
    float4 v = *(const float4*)&x[(size_t)g * Nn * 64 + i * 4];
    ushort4 u = make_ushort4(f2bf(v.x * dc), f2bf(v.y * dc), f2bf(v.z * dc), f2bf(v.w * dc));
    *(ushort4*)&xbs[(size_t)g * Nn * 64 + i * 4] = u;
}

// ---------------- agg 64-feat: rolling 4-edge steps, 1-deep gather pipeline (bf16) ----------------
__global__ __launch_bounds__(256) void k_agg1(const unsigned short* __restrict__ xs_, const int* __restrict__ off_,
                                              const unsigned short* __restrict__ srcs_,
                                              const float* __restrict__ dinv_, unsigned short* __restrict__ z1_) {
    int g = blockIdx.y;
    const unsigned short* xs = xs_ + (size_t)g * Nn * 64;
    const int* off = off_ + g * (Nn + 1);
    const unsigned short* srcs = srcs_ + (size_t)g * En;
    unsigned short* z1 = z1_ + (size_t)g * Nn * 64;
    int node = blockIdx.x * 8 + (threadIdx.x >> 5);
    int lane = threadIdx.x & 31;
    int sub = lane >> 3;   // edge slot 0..3
    int fo = lane & 7;     // feature octile: feats [fo*8, fo*8+8)
    int beg = off[node], end = off[node + 1];
    int d = end - beg;
    int dm1 = max(d - 1, 0);
    int nst = (d + 3) >> 2;            // uniform step count within 32-lane group
    float acc[8] = {};
    int sb = srcs[beg + min(sub, dm1)];
    v8s c = *(const v8s*)&xs[(long)sb * 64 + fo * 8];
    sb = srcs[beg + min(4 + sub, dm1)];
    for (int st = 0; st < nst; ++st) {
        v8s n = *(const v8s*)&xs[(long)sb * 64 + fo * 8];
        sb = srcs[beg + min((st + 2) * 4 + sub, dm1)];
        float m = (st * 4 + sub < d) ? 1.f : 0.f;
#pragma unroll
        for (int q = 0; q < 8; ++q) acc[q] += m * bf2f((unsigned short)c[q]);
        c = n;
    }
#pragma unroll
    for (int q = 0; q < 8; ++q) {
        acc[q] += __shfl_xor(acc[q], 8, 32);
        acc[q] += __shfl_xor(acc[q], 16, 32);
    }
    if (sub == 0) {
        float dc = dinv_[g * Nn + node];
        v8s ow = *(const v8s*)&xs[(long)node * 64 + fo * 8];
        ushort4 o0, o1;
        o0.x = f2bf((acc[0] + bf2f((unsigned short)ow[0])) * dc);
        o0.y = f2bf((acc[1] + bf2f((unsigned short)ow[1])) * dc);
        o0.z = f2bf((acc[2] + bf2f((unsigned short)ow[2])) * dc);
        o0.w = f2bf((acc[3] + bf2f((unsigned short)ow[3])) * dc);
        o1.x = f2bf((acc[4] + bf2f((unsigned short)ow[4])) * dc);
        o1.y = f2bf((acc[5] + bf2f((unsigned short)ow[5])) * dc);
        o1.z = f2bf((acc[6] + bf2f((unsigned short)ow[6])) * dc);
        o1.w = f2bf((acc[7] + bf2f((unsigned short)ow[7])) * dc);
        *(ushort4*)&z1[(long)node * 64 + fo * 8] = o0;
        *(ushort4*)&z1[(long)node * 64 + fo * 8 + 4] = o1;
    }
}

// ---------------- agg 128-feat: rolling 4-edge steps over FP8 table (half gather bytes) ----------------
__global__ __launch_bounds__(256) void k_agg2(const unsigned char* __restrict__ h8_, const int* __restrict__ off_,
                                              const unsigned short* __restrict__ srcs_,
                                              const float* __restrict__ dinv_, unsigned short* __restrict__ z2_) {
    int g = blockIdx.y;
    const unsigned char* h8 = h8_ + (size_t)g * Nn * 128;
    const int* off = off_ + g * (Nn + 1);
    const unsigned short* srcs = srcs_ + (size_t)g * En;
    unsigned short* z2 = z2_ + (size_t)g * Nn * 128;
    int node = blockIdx.x * 8 + (threadIdx.x >> 5);
    int lane = threadIdx.x & 31;
    int sub = lane >> 3;   // edge slot 0..3
    int fo = lane & 7;     // feature 16-tile: feats [fo*16, fo*16+16) as 16 fp8 bytes
    int beg = off[node], end = off[node + 1];
    int d = end - beg;
    int dm1 = max(d - 1, 0);
    int nst = (d + 3) >> 2;
    v2f acc[8] = {};
    int sb = srcs[beg + min(sub, dm1)];
    uint4 c = *(const uint4*)&h8[(unsigned)sb * 128 + fo * 16];
    sb = srcs[beg + min(4 + sub, dm1)];
    for (int st = 0; st < nst; ++st) {
        uint4 n = *(const uint4*)&h8[(unsigned)sb * 128 + fo * 16];
        sb = srcs[beg + min((st + 2) * 4 + sub, dm1)];
        float m = (st * 4 + sub < d) ? 1.f : 0.f;
        v2f m2 = {m, m};
        acc[0] += m2 * fp8pk<false>(c.x);
        acc[1] += m2 * fp8pk<true>(c.x);
        acc[2] += m2 * fp8pk<false>(c.y);
        acc[3] += m2 * fp8pk<true>(c.y);
        acc[4] += m2 * fp8pk<false>(c.z);
        acc[5] += m2 * fp8pk<true>(c.z);
        acc[6] += m2 * fp8pk<false>(c.w);
        acc[7] += m2 * fp8pk<true>(c.w);
        c = n;
    }
#pragma unroll
    for (int p = 0; p < 8; ++p) {
        float ax = acc[p].x, ay = acc[p].y;
        ax += __shfl_xor(ax, 8, 32);  ay += __shfl_xor(ay, 8, 32);
        ax += __shfl_xor(ax, 16, 32); ay += __shfl_xor(ay, 16, 32);
        acc[p].x = ax; acc[p].y = ay;
    }
    if (sub == 0) {
        float dc = dinv_[g * Nn + node];
        uint4 ow = *(const uint4*)&h8[(unsigned)node * 128 + fo * 16];
        v2f sp0 = fp8pk<false>(ow.x), sp1 = fp8pk<true>(ow.x);
        v2f sp2 = fp8pk<false>(ow.y), sp3 = fp8pk<true>(ow.y);
        v2f sp4 = fp8pk<false>(ow.z), sp5 = fp8pk<true>(ow.z);
        v2f sp6 = fp8pk<false>(ow.w), sp7 = fp8pk<true>(ow.w);
        unsigned short* zp = &z2[(long)node * 128 + fo * 16];
        ushort4 o;
        o.x = f2bf((acc[0].x + sp0.x) * dc); o.y = f2bf((acc[0].y + sp0.y) * dc);
        o.z = f2bf((acc[1].x + sp1.x) * dc); o.w = f2bf((acc[1].y + sp1.y) * dc);
        *(ushort4*)(zp + 0) = o;
        o.x = f2bf((acc[2].x + sp2.x) * dc); o.y = f2bf((acc[2].y + sp2.y) * dc);
        o.z = f2bf((acc[3].x + sp3.x) * dc); o.w = f2bf((acc[3].y + sp3.y) * dc);
        *(ushort4*)(zp + 4) = o;
        o.x = f2bf((acc[4].x + sp4.x) * dc); o.y = f2bf((acc[4].y + sp4.y) * dc);
        o.z = f2bf((acc[5].x + sp5.x) * dc); o.w = f2bf((acc[5].y + sp5.y) * dc);
        *(ushort4*)(zp + 8) = o;
        o.x = f2bf((acc[6].x + sp6.x) * dc); o.y = f2bf((acc[6].y + sp6.y) * dc);
        o.z = f2bf((acc[7].x + sp7.x) * dc); o.w = f2bf((acc[7].y + sp7.y) * dc);
        *(ushort4*)(zp + 12) = o;
    }
}

// ---------------- MFMA mm, all graphs: out = relu(zin@W + b); SCALE path writes fp8*dinv ----------------
template <int K, bool SCALE>
__global__ __launch_bounds__(256) void k_mmfma(const unsigned short* __restrict__ zin_,
                                               const float* __restrict__ W, const float* __restrict__ bias,
                                               const float* __restrict__ dinv_,
                                               unsigned short* __restrict__ outp_) {
    __shared__ __align__(16) unsigned short Wt[128 * (K + 8)];
    __shared__ __align__(16) unsigned short At[32 * (K + 8)];
    int g = blockIdx.y;
    const unsigned short* zin = zin_ + (size_t)g * Nn * K;
    const float* dinv = dinv_ + g * Nn;
    unsigned short* outp = outp_ + (size_t)g * Nn * 128;
    unsigned char* out8 = ((unsigned char*)outp_) + (size_t)g * Nn * 128;
    int t = threadIdx.x;
    int base = blockIdx.x * 32;

#pragma unroll
    for (int i = 0; i < K * 128 / 256; ++i) {
        int idx = i * 256 + t;
        int k = idx >> 7, n = idx & 127;
        Wt[n * (K + 8) + k] = f2bf(W[idx]);
    }
    {
        int r = t >> 3, cb = (t & 7) * (K / 8);
        long grow = base + r;
#pragma unroll
        for (int j = 0; j < K / 32; ++j) {
            ushort4 u = make_ushort4(0, 0, 0, 0);
            if (grow < Nn) u = *(const ushort4*)&zin[grow * K + cb + j * 4];
            *(ushort4*)&At[r * (K + 8) + cb + j * 4] = u;
        }
    }
    __syncthreads();

    int w = t >> 6, lane = t & 63;
    int wm = w & 1, wn = w >> 1;
    int m = lane & 15, q = lane >> 4;
    v4f acc[4] = {};
    const unsigned short* Ap = &At[(wm * 16 + m) * (K + 8) + q * 8];
    const unsigned short* Bp = &Wt[(wn * 64 + m) * (K + 8) + q * 8];
    const int rstep = 16 * (K + 8);
#pragma unroll
    for (int ks = 0; ks < K / 32; ++ks) {
        v8s a = *(const v8s*)(Ap + ks * 32);
        v8s b0 = *(const v8s*)(Bp + 0 * rstep + ks * 32);
        v8s b1 = *(const v8s*)(Bp + 1 * rstep + ks * 32);
        v8s b2 = *(const v8s*)(Bp + 2 * rstep + ks * 32);
        v8s b3 = *(const v8s*)(Bp + 3 * rstep + ks * 32);
        acc[0] = __builtin_amdgcn_mfma_f32_16x16x32_bf16(a, b0, acc[0], 0, 0, 0);
        acc[1] = __builtin_amdgcn_mfma_f32_16x16x32_bf16(a, b1, acc[1], 0, 0, 0);
        acc[2] = __builtin_amdgcn_mfma_f32_16x16x32_bf16(a, b2, acc[2], 0, 0, 0);
        acc[3] = __builtin_amdgcn_mfma_f32_16x16x32_bf16(a, b3, acc[3], 0, 0, 0);
    }

    int col0 = wn * 64 + m;
    int rbase = base + wm * 16 + q * 4;
    float dv[4];
#pragma unroll
    for (int rg = 0; rg < 4; ++rg)
        dv[rg] = SCALE ? ((rbase + rg < Nn) ? dinv[rbase + rg] : 1.f) : 1.f;
#pragma unroll
    for (int nt = 0; nt < 4; ++nt) {
        float bc = bias[col0 + nt * 16];
#pragma unroll
        for (int rg = 0; rg < 4; ++rg) {
            int row = rbase + rg;
            if (row < Nn) {
                float o = fmaxf(acc[nt][rg] + bc, 0.f);
                if (SCALE)
                    out8[(long)row * 128 + col0 + nt * 16] = f2fp8(o * dv[rg]);
                else
                    outp[(long)row * 128 + col0 + nt * 16] = f2bf(o);
            }
        }
    }
}

// ---------------- segment mean pool (batch sorted), all graphs ----------------
__global__ __launch_bounds__(128) void k_pool(const unsigned short* __restrict__ y_, const int* __restrict__ bat,
                                              float* __restrict__ emb_sum, float* __restrict__ cnt) {
    int g = blockIdx.y;
    const unsigned short* y = y_ + (size_t)g * Nn * 128;
    const int* batch = bat + (size_t)g * Nn;
    int f = threadIdx.x;
    int start = blockIdx.x * 64;
    int end = min(start + 64, Nn);
    if (start >= Nn) return;
    float acc = 0.f;
    int cacc = 0;
    int cur = batch[start];
    for (int i = start; i < end; ++i) {
        int b = batch[i];
        if (b != cur) {
            atomicAdd(&emb_sum[(g * Bq + cur) * Hn + f], acc);
            if (f == 0) atomicAdd(&cnt[g * Bq + cur], (float)cacc);
            acc = 0.f; cacc = 0; cur = b;
        }
        acc += bf2f(y[(long)i * Hn + f]);
        cacc++;
    }
    atomicAdd(&emb_sum[(g * Bq + cur) * Hn + f], acc);
    if (f == 0) atomicAdd(&cnt[g * Bq + cur], (float)cacc);
}

// ---------------- whole MHA: one block per batch element b ----------------
__global__ __launch_bounds__(128) void k_attn(const float* __restrict__ emb_sum, const float* __restrict__ cnt,
                                              const float* __restrict__ ipw, const float* __restrict__ ipb,
                                              const float* __restrict__ opw, const float* __restrict__ opb,
                                              float* __restrict__ pooled) {
    int b = blockIdx.x;
    int f = threadIdx.x;
    __shared__ float es[4][128], qs[4][128], ks[4][128], vs[4][128], sc[128], cx[4][128];
#pragma unroll
    for (int g = 0; g < 4; ++g) {
        float c = cnt[g * Bq + b];
        es[g][f] = (c > 0.f) ? emb_sum[(g * Bq + b) * Hn + f] / c : 0.f;
    }
    __syncthreads();
#pragma unroll
    for (int g = 0; g < 4; ++g) {
        float q = ipb[f], k = ipb[Hn + f], v = ipb[2 * Hn + f];
        for (int j = 0; j < Hn; ++j) {
            float e = es[g][j];
            q += e * ipw[f * Hn + j];
            k += e * ipw[(Hn + f) * Hn + j];
            v += e * ipw[(2 * Hn + f) * Hn + j];
        }
        qs[g][f] = q; ks[g][f] = k; vs[g][f] = v;
    }
    __syncthreads();
    {
        int h = f >> 4, g = (f >> 2) & 3, kk = f & 3;
        float s = 0.f;
        for (int d = 0; d < 16; ++d) s += qs[g][h * 16 + d] * ks[kk][h * 16 + d];
        sc[f] = s * 0.25f;
    }
    __syncthreads();
    {
        int h = f >> 4;
#pragma unroll
        for (int g = 0; g < 4; ++g) {
            int bi = h * 16 + g * 4;
            float s0 = sc[bi], s1 = sc[bi + 1], s2 = sc[bi + 2], s3 = sc[bi + 3];
            float m = fmaxf(fmaxf(s0, s1), fmaxf(s2, s3));
            float e0 = __expf(s0 - m), e1 = __expf(s1 - m), e2 = __expf(s2 - m), e3 = __expf(s3 - m);
            float rinv = 1.f / (e0 + e1 + e2 + e3);
            cx[g][f] = (e0 * vs[0][f] + e1 * vs[1][f] + e2 * vs[2][f] + e3 * vs[3][f]) * rinv;
        }
    }
    __syncthreads();
#pragma unroll
    for (int g = 0; g < 4; ++g) {
        float a = opb[f];
        for (int j = 0; j < Hn; ++j) a += cx[g][j] * opw[f * Hn + j];
        atomicAdd(&pooled[g * Hn + f], a * (1.0f / Bq));
    }
}

// ---------------- final: out[g,n] = (pooled[g] . lin_w[n] + lin_b[n]) * 60 + 50 ----------------
__global__ __launch_bounds__(256) void k_final(const float* __restrict__ pooled, const float* __restrict__ lw,
                                               const float* __restrict__ lb, float* __restrict__ out) {
    __shared__ float ps[512];
    int t = threadIdx.x;
    ps[t] = pooled[t];
    ps[t + 256] = pooled[t + 256];
    __syncthreads();
    int wave = t >> 6, lane = t & 63;
    int n = blockIdx.x * 4 + wave;
    if (n >= NNODES) return;
    float2 w = *(const float2*)&lw[(long)n * 128 + lane * 2];
    float a0 = w.x * ps[0 * 128 + lane * 2] + w.y * ps[0 * 128 + lane * 2 + 1];
    float a1 = w.x * ps[1 * 128 + lane * 2] + w.y * ps[1 * 128 + lane * 2 + 1];
    float a2 = w.x * ps[2 * 128 + lane * 2] + w.y * ps[2 * 128 + lane * 2 + 1];
    float a3 = w.x * ps[3 * 128 + lane * 2] + w.y * ps[3 * 128 + lane * 2 + 1];
#pragma unroll
    for (int off = 32; off > 0; off >>= 1) {
        a0 += __shfl_down(a0, off);
        a1 += __shfl_down(a1, off);
        a2 += __shfl_down(a2, off);
        a3 += __shfl_down(a3, off);
    }
    if (lane == 0) {
        float bn = lb[n];
        out[0 * NNODES + n] = (a0 + bn) * 60.f + 50.f;
        out[1 * NNODES + n] = (a1 + bn) * 60.f + 50.f;
        out[2 * NNODES + n] = (a2 + bn) * 60.f + 50.f;
        out[3 * NNODES + n] = (a3 + bn) * 60.f + 50.f;
    }
}

extern "C" void kernel_launch(void* const* d_in, const int* in_sizes, int n_in,
                              void* d_out, int out_size, void* d_ws, size_t ws_size,
                              hipStream_t stream) {
    const float* x   = (const float*)d_in[0];
    const int*   ei  = (const int*)d_in[1];
    const int*   bat = (const int*)d_in[2];
    const float* W1  = (const float*)d_in[3];
    const float* b1  = (const float*)d_in[4];
    const float* W2  = (const float*)d_in[5];
    const float* b2  = (const float*)d_in[6];
    const float* ipw = (const float*)d_in[7];
    const float* ipb = (const float*)d_in[8];
    const float* opw = (const float*)d_in[9];
    const float* opb = (const float*)d_in[10];
    const float* lw  = (const float*)d_in[11];
    const float* lb  = (const float*)d_in[12];
    float* out = (float*)d_out;

    // workspace carve-up (~214 MB)
    char* p = (char*)d_ws;
    unsigned short* xbs = (unsigned short*)p;                 // [4][N,64]  bf16  25.6 MB
    unsigned short* z1  = (unsigned short*)(p + 25600000);    // [4][N,64]  bf16  25.6 MB
    unsigned char*  y1f8 = (unsigned char*)(p + 51200000);    // [4][N,128] fp8   25.6 MB (in y1b slot)
    unsigned short* z2  = (unsigned short*)(p + 102400000);   // [4][N,128] bf16  51.2 MB
    unsigned int*   pairs = (unsigned int*)(p + 102400000);   // [4][E] uint 12.8 MB (alias z2; dead before agg2)
    int* chist = (int*)(p + 102400000 + (size_t)4 * En * 4);  // [4][EB][NBK] int 307 KB (alias z2 tail; dead before agg2)
    unsigned short* y2b = (unsigned short*)(p + 153600000);   // [4][N,128] bf16  51.2 MB
    char* meta = p + 204800000;
    int*   off  = (int*)meta;                                 // [4][N+1]
    float* dinv = (float*)(off + 4 * (Nn + 1));               // [4][N]
    int*   btot  = (int*)(dinv + 4 * Nn);                     // [4][NBK]
    int*   bbase = btot + 4 * NBK;                            // [4][NBK]
    int*   bcur  = bbase + 4 * NBK;                           // [4][NBK]
    unsigned short* srcs = (unsigned short*)(bcur + 4 * NBK); // [4][E] ushort 6.4 MB
    float* emb    = (float*)(srcs + (size_t)4 * En);          // [G,B,H]
    float* cnt    = emb + Gn * Bq * Hn;                       // [G,B]
    float* pooled = cnt + Gn * Bq;                            // [G,H]

    hipMemsetAsync(btot, 0, 4 * NBK * sizeof(int), stream);
    hipMemsetAsync(emb, 0, Gn * Bq * Hn * sizeof(float), stream);
    hipMemsetAsync(cnt, 0, Gn * Bq * sizeof(float), stream);
    hipMemsetAsync(pooled, 0, Gn * Hn * sizeof(float), stream);

    const int agGrid = (Nn + 7) / 8;                 // 6250
    const int mmGrid = (Nn + 31) / 32;               // 1563
    const int plGrid = (Nn + 63) / 64;               // 782
    const int ctGrid = (Nn * 16 + 255) / 256;        // 3125

    // CSR build: totals+chunk hists -> bases -> bucketize (hist reuse) -> fused fill
    k_btot<<<dim3(EB, Gn), 256, 0, stream>>>(ei, btot, chist);
    k_bbase<<<Gn, 256, 0, stream>>>(btot, bbase, bcur);
    k_bucket<<<dim3(EB, Gn), 256, 0, stream>>>(ei, bcur, pairs, chist);
    k_fillb2<<<dim3(NBK, Gn), 256, 0, stream>>>(pairs, bbase, btot, off, dinv, srcs);

    // GCN layers, all graphs per launch
    k_cast<<<dim3(ctGrid, Gn), 256, 0, stream>>>(x, dinv, xbs);
    k_agg1<<<dim3(agGrid, Gn), 256, 0, stream>>>(xbs, off, srcs, dinv, z1);
    k_mmfma<64, true><<<dim3(mmGrid, Gn), 256, 0, stream>>>(z1, W1, b1, dinv, (unsigned short*)y1f8);
    k_agg2<<<dim3(agGrid, Gn), 256, 0, stream>>>(y1f8, off, srcs, dinv, z2);
    k_mmfma<128, false><<<dim3(mmGrid, Gn), 256, 0, stream>>>(z2, W2, b2, dinv, y2b);
    k_pool<<<dim3(plGrid, Gn), 128, 0, stream>>>(y2b, bat, emb, cnt);

    k_attn<<<Bq, 128, 0, stream>>>(emb, cnt, ipw, ipb, opw, opb, pooled);
    k_final<<<(NNODES + 3) / 4, 256, 0, stream>>>(pooled, lw, lb, out);
}